// Round 1
// baseline (12321.210 us; speedup 1.0000x reference)
//
#include <hip/hip_runtime.h>
#include <math.h>

// GPT forward w/ learned token pruning. fp32 throughout (mask bits are
// numerically fragile: imp ~1e-3 vs th ~1e-4; bf16 would risk mask flips
// vs the fp32 numpy reference).

#define LNUM 12
#define HNUM 12
#define CDIM 768
#define HSD  64
#define VDIM 50304
#define TDIM 1024
#define BDIM 2
#define NROWS 2048   // B*T

// ---------- block reduction (256 threads) ----------
__device__ __forceinline__ float bred(float v, int op) {  // op: 0 sum, 1 max
  __shared__ float red[256];
  const int tid = threadIdx.x;
  red[tid] = v;
  __syncthreads();
#pragma unroll
  for (int s = 128; s > 0; s >>= 1) {
    if (tid < s) {
      float o = red[tid + s];
      red[tid] = op ? fmaxf(red[tid], o) : (red[tid] + o);
    }
    __syncthreads();
  }
  float r = red[0];
  __syncthreads();
  return r;
}

// ---------- embedding + am init ----------
__global__ void k_embed(const int* __restrict__ idx, const float* __restrict__ wte,
                        const float* __restrict__ wpe, float* __restrict__ x,
                        float* __restrict__ am) {
  const int row = blockIdx.x;
  const int t = row & (TDIM - 1);
  const long tok = idx[row];
  const float* src = wte + tok * CDIM;
  const float* pp = wpe + (long)t * CDIM;
  float* dst = x + (long)row * CDIM;
  for (int c = threadIdx.x; c < CDIM; c += 256) dst[c] = src[c] + pp[c];
  if (threadIdx.x == 0) am[row] = 1.0f;
}

// ---------- layernorm (block per row, C=768 = 3*256) ----------
__global__ void k_layernorm(const float* __restrict__ in, const float* __restrict__ w,
                            const float* __restrict__ b, float* __restrict__ out) {
  const long row = blockIdx.x;
  const int tid = threadIdx.x;
  const float* xr = in + row * CDIM;
  float v0 = xr[tid], v1 = xr[tid + 256], v2 = xr[tid + 512];
  float mean = bred(v0 + v1 + v2, 0) * (1.0f / CDIM);
  float d0 = v0 - mean, d1 = v1 - mean, d2 = v2 - mean;
  float var = bred(d0 * d0 + d1 * d1 + d2 * d2, 0) * (1.0f / CDIM);
  float inv = 1.0f / sqrtf(var + 1e-5f);
  float* orow = out + row * CDIM;
  orow[tid]       = d0 * inv * w[tid]       + b[tid];
  orow[tid + 256] = d1 * inv * w[tid + 256] + b[tid + 256];
  orow[tid + 512] = d2 * inv * w[tid + 512] + b[tid + 512];
}

// ---------- generic fp32 GEMM: C = beta*C + alpha*(A@B[^T]) + bias, opt GELU ----------
// 64x64 tile, BK=16, 256 thr, 4x4 per thread. Batched via blockIdx.z with
// two-level (b,h) strides. All M,N multiples of 64 and K of 16 (asserted by shapes).
template <int BT, int ACT>
__global__ __launch_bounds__(256) void k_gemm(
    const float* __restrict__ A, const float* __restrict__ B,
    const float* __restrict__ bias, float* __restrict__ C,
    int K, int lda, int ldb, int ldc,
    long sAb, long sAh, long sBb, long sBh, long sCb, long sCh,
    int Hb, float alpha, int beta) {
  const int bid = blockIdx.z;
  const int bb = bid / Hb, hh = bid - bb * Hb;
  A += bb * sAb + hh * sAh;
  B += bb * sBb + hh * sBh;
  C += bb * sCb + hh * sCh;
  const int m0 = blockIdx.y << 6, n0 = blockIdx.x << 6;
  __shared__ float As[16][68];
  __shared__ float Bs[16][68];
  const int tid = threadIdx.x;
  const int r0 = (tid >> 4) << 2;   // acc row base
  const int c0 = (tid & 15) << 2;   // acc col base
  const int lr = tid >> 2;          // 0..63 (tile row for loads)
  const int lk = (tid & 3) << 2;    // 0,4,8,12 (k offset for loads)
  const int bk = tid >> 4;          // 0..15
  const int bn = (tid & 15) << 2;   // 0..60
  float acc[4][4] = {{0.f, 0.f, 0.f, 0.f}, {0.f, 0.f, 0.f, 0.f},
                     {0.f, 0.f, 0.f, 0.f}, {0.f, 0.f, 0.f, 0.f}};
  for (int k0 = 0; k0 < K; k0 += 16) {
    float4 av = *(const float4*)(A + (long)(m0 + lr) * lda + (k0 + lk));
    As[lk][lr] = av.x; As[lk + 1][lr] = av.y; As[lk + 2][lr] = av.z; As[lk + 3][lr] = av.w;
    if (BT) {
      float4 bv = *(const float4*)(B + (long)(n0 + lr) * ldb + (k0 + lk));
      Bs[lk][lr] = bv.x; Bs[lk + 1][lr] = bv.y; Bs[lk + 2][lr] = bv.z; Bs[lk + 3][lr] = bv.w;
    } else {
      *(float4*)&Bs[bk][bn] = *(const float4*)(B + (long)(k0 + bk) * ldb + (n0 + bn));
    }
    __syncthreads();
#pragma unroll
    for (int kk = 0; kk < 16; ++kk) {
      float4 a = *(const float4*)&As[kk][r0];
      float4 bv = *(const float4*)&Bs[kk][c0];
      acc[0][0] += a.x * bv.x; acc[0][1] += a.x * bv.y; acc[0][2] += a.x * bv.z; acc[0][3] += a.x * bv.w;
      acc[1][0] += a.y * bv.x; acc[1][1] += a.y * bv.y; acc[1][2] += a.y * bv.z; acc[1][3] += a.y * bv.w;
      acc[2][0] += a.z * bv.x; acc[2][1] += a.z * bv.y; acc[2][2] += a.z * bv.z; acc[2][3] += a.z * bv.w;
      acc[3][0] += a.w * bv.x; acc[3][1] += a.w * bv.y; acc[3][2] += a.w * bv.z; acc[3][3] += a.w * bv.w;
    }
    __syncthreads();
  }
  float4 bs4 = make_float4(0.f, 0.f, 0.f, 0.f);
  if (bias) bs4 = *(const float4*)(bias + n0 + c0);
#pragma unroll
  for (int i = 0; i < 4; ++i) {
    float* cp = C + (long)(m0 + r0 + i) * ldc + (n0 + c0);
    float4 prev = make_float4(0.f, 0.f, 0.f, 0.f);
    if (beta) prev = *(const float4*)cp;
    float4 o;
    o.x = prev.x + alpha * acc[i][0] + bs4.x;
    o.y = prev.y + alpha * acc[i][1] + bs4.y;
    o.z = prev.z + alpha * acc[i][2] + bs4.z;
    o.w = prev.w + alpha * acc[i][3] + bs4.w;
    if (ACT == 1) {  // exact GELU: 0.5*x*(1+erf(x/sqrt(2)))
      o.x = 0.5f * o.x * (1.0f + erff(o.x * 0.70710678118654752f));
      o.y = 0.5f * o.y * (1.0f + erff(o.y * 0.70710678118654752f));
      o.z = 0.5f * o.z * (1.0f + erff(o.z * 0.70710678118654752f));
      o.w = 0.5f * o.w * (1.0f + erff(o.w * 0.70710678118654752f));
    }
    *(float4*)cp = o;
  }
}

// ---------- masked softmax over keys; block per (q, b*h) row ----------
__global__ void k_softmax(float* __restrict__ att, const float* __restrict__ am) {
  const int q = blockIdx.x;
  const int bh = blockIdx.y;
  const int b = bh / HNUM;
  float* row = att + ((long)bh * TDIM + q) * TDIM;
  const float* amr = am + b * TDIM;
  const int tid = threadIdx.x;
  float lv[4];
  bool valid[4];
  float mx = -INFINITY;
#pragma unroll
  for (int i = 0; i < 4; ++i) {
    const int k = tid + (i << 8);
    const bool ok = (k <= q) && (amr[k] > 0.0f);
    valid[i] = ok;
    lv[i] = ok ? row[k] : -INFINITY;
    mx = fmaxf(mx, lv[i]);
  }
  mx = bred(mx, 1);
  float sum = 0.f;
#pragma unroll
  for (int i = 0; i < 4; ++i) {
    lv[i] = valid[i] ? expf(lv[i] - mx) : 0.0f;
    sum += lv[i];
  }
  sum = bred(sum, 0);
  const float inv = sum > 0.f ? 1.0f / sum : 0.0f;
#pragma unroll
  for (int i = 0; i < 4; ++i) row[tid + (i << 8)] = lv[i] * inv;
}

// ---------- imp[b,k] partial column sums of att ----------
__global__ void k_impsum(const float* __restrict__ att, float* __restrict__ imp) {
  const int h = blockIdx.x >> 2, qc = blockIdx.x & 3;
  const int b = blockIdx.z;
  const int k = (blockIdx.y << 8) + threadIdx.x;
  const float* base = att + (((long)(b * HNUM + h) * TDIM) + (qc << 8)) * TDIM + k;
  float s = 0.f;
#pragma unroll 4
  for (int q = 0; q < 256; ++q) s += base[(long)q * TDIM];
  atomicAdd(&imp[b * TDIM + k], s);
}

// ---------- threshold mask: cm = am*pm (protect last 64); x *= cm; am = cm ----------
__global__ void k_mask(const float* __restrict__ imp, const float* __restrict__ thp,
                       float* __restrict__ am, float* __restrict__ x) {
  const int row = blockIdx.x;
  const int t = row & (TDIM - 1);
  const float impv = imp[row] * (1.0f / (HNUM * TDIM));
  float pm = (impv >= *thp) ? 1.0f : 0.0f;
  if (t >= TDIM - 64) pm = 1.0f;
  const float cm = am[row] * pm;
  float* xr = x + (long)row * CDIM;
  const int tid = threadIdx.x;
  xr[tid] *= cm;
  xr[tid + 256] *= cm;
  xr[tid + 512] *= cm;
  if (tid == 0) am[row] = cm;
}

// ---------- loss: per-row logsumexp + NLL ----------
__global__ void k_lossrow(const float* __restrict__ logits, const int* __restrict__ tgt,
                          float* __restrict__ nll) {
  const int row = blockIdx.x;
  const float* lr = logits + (long)row * VDIM;
  const int tid = threadIdx.x;
  float mx = -INFINITY;
  for (int k = tid; k < VDIM; k += 256) mx = fmaxf(mx, lr[k]);
  mx = bred(mx, 1);
  float s = 0.f;
  for (int k = tid; k < VDIM; k += 256) s += expf(lr[k] - mx);
  s = bred(s, 0);
  if (tid == 0) {
    const int t = tgt[row];
    nll[row] = (t != -1) ? -(lr[t] - mx - logf(s)) : 0.0f;
  }
}

__global__ void k_lossfinal(const float* __restrict__ nll, const int* __restrict__ tgt,
                            float* __restrict__ out) {
  const int tid = threadIdx.x;
  float s = 0.f, cnt = 0.f;
  for (int r = tid; r < NROWS; r += 256) {
    s += nll[r];
    cnt += (tgt[r] != -1) ? 1.f : 0.f;
  }
  s = bred(s, 0);
  cnt = bred(cnt, 0);
  if (tid == 0) out[0] = s / cnt;
}

extern "C" void kernel_launch(void* const* d_in, const int* in_sizes, int n_in,
                              void* d_out, int out_size, void* d_ws, size_t ws_size,
                              hipStream_t stream) {
  (void)in_sizes; (void)n_in; (void)out_size; (void)ws_size;
  const int* idx      = (const int*)d_in[0];
  const int* targets  = (const int*)d_in[1];
  const float* wte    = (const float*)d_in[2];
  const float* wpe    = (const float*)d_in[3];
  const float* ln1_w  = (const float*)d_in[4];
  const float* ln1_b  = (const float*)d_in[5];
  const float* attn_w = (const float*)d_in[6];
  const float* attn_b = (const float*)d_in[7];
  const float* proj_w = (const float*)d_in[8];
  const float* proj_b = (const float*)d_in[9];
  const float* ln2_w  = (const float*)d_in[10];
  const float* ln2_b  = (const float*)d_in[11];
  const float* fc_w   = (const float*)d_in[12];
  const float* fc_b   = (const float*)d_in[13];
  const float* mlp_w  = (const float*)d_in[14];
  const float* mlp_b  = (const float*)d_in[15];
  const float* thres  = (const float*)d_in[16];
  const float* lnf_w  = (const float*)d_in[17];
  const float* lnf_b  = (const float*)d_in[18];
  float* logits = (float*)d_out;
  float* loss = logits + (long)NROWS * VDIM;

  // workspace layout (fp32), total ~41M floats = 164 MB
  float* x    = (float*)d_ws;
  float* h    = x + (long)NROWS * CDIM;
  float* qkv  = h + (long)NROWS * CDIM;
  float* att  = qkv + (long)NROWS * 3 * CDIM;
  float* ybuf = att + (long)BDIM * HNUM * TDIM * TDIM;
  float* act  = ybuf + (long)NROWS * CDIM;
  float* am   = act + (long)NROWS * 4 * CDIM;
  float* imp  = am + NROWS;
  float* nll  = imp + NROWS;

  k_embed<<<NROWS, 256, 0, stream>>>(idx, wte, wpe, x, am);

  for (int l = 0; l < LNUM; ++l) {
    k_layernorm<<<NROWS, 256, 0, stream>>>(x, ln1_w + l * CDIM, ln1_b + l * CDIM, h);
    // qkv = h @ attn_w[l] + attn_b[l]   (2048x2304, K=768)
    k_gemm<0, 0><<<dim3(36, 32, 1), 256, 0, stream>>>(
        h, attn_w + (long)l * CDIM * 3 * CDIM, attn_b + (long)l * 3 * CDIM, qkv,
        768, 768, 2304, 2304, 0, 0, 0, 0, 0, 0, 1, 1.0f, 0);
    // scores = q @ k^T / 8   batched over 24 (b,h): 1024x1024, K=64
    k_gemm<1, 0><<<dim3(16, 16, 24), 256, 0, stream>>>(
        qkv, qkv + CDIM, nullptr, att,
        64, 2304, 2304, 1024,
        (long)TDIM * 3 * CDIM, 64, (long)TDIM * 3 * CDIM, 64,
        (long)HNUM * TDIM * TDIM, (long)TDIM * TDIM, HNUM, 0.125f, 0);
    k_softmax<<<dim3(TDIM, BDIM * HNUM), 256, 0, stream>>>(att, am);
    hipMemsetAsync(imp, 0, NROWS * sizeof(float), stream);
    k_impsum<<<dim3(HNUM * 4, 4, BDIM), 256, 0, stream>>>(att, imp);
    // y = att @ v   batched: 1024x64, K=1024 -> ybuf (B,T,C) at head offset
    k_gemm<0, 0><<<dim3(1, 16, 24), 256, 0, stream>>>(
        att, qkv + 2 * CDIM, nullptr, ybuf,
        1024, 1024, 2304, 768,
        (long)HNUM * TDIM * TDIM, (long)TDIM * TDIM, (long)TDIM * 3 * CDIM, 64,
        (long)TDIM * CDIM, 64, HNUM, 1.0f, 0);
    // x += ybuf @ proj_w[l] + proj_b[l]
    k_gemm<0, 0><<<dim3(12, 32, 1), 256, 0, stream>>>(
        ybuf, proj_w + (long)l * CDIM * CDIM, proj_b + (long)l * CDIM, x,
        768, 768, 768, 768, 0, 0, 0, 0, 0, 0, 1, 1.0f, 1);
    // token pruning mask (after residual add, matching reference order)
    k_mask<<<NROWS, 256, 0, stream>>>(imp, thres + l, am, x);
    k_layernorm<<<NROWS, 256, 0, stream>>>(x, ln2_w + l * CDIM, ln2_b + l * CDIM, h);
    // act = gelu(h @ fc_w[l] + fc_b[l])   (2048x3072, K=768)
    k_gemm<0, 1><<<dim3(48, 32, 1), 256, 0, stream>>>(
        h, fc_w + (long)l * CDIM * 4 * CDIM, fc_b + (long)l * 4 * CDIM, act,
        768, 768, 3072, 3072, 0, 0, 0, 0, 0, 0, 1, 1.0f, 0);
    // x += act @ mlp_w[l] + mlp_b[l]   (2048x768, K=3072)
    k_gemm<0, 0><<<dim3(12, 32, 1), 256, 0, stream>>>(
        act, mlp_w + (long)l * 4 * CDIM * CDIM, mlp_b + (long)l * CDIM, x,
        3072, 3072, 768, 768, 0, 0, 0, 0, 0, 0, 1, 1.0f, 1);
  }

  k_layernorm<<<NROWS, 256, 0, stream>>>(x, lnf_w, lnf_b, h);
  // logits = h @ wte^T   (2048x50304, K=768); 50304 = 786*64
  k_gemm<1, 0><<<dim3(786, 32, 1), 256, 0, stream>>>(
      h, wte, nullptr, logits,
      768, 768, 768, VDIM, 0, 0, 0, 0, 0, 0, 1, 1.0f, 0);
  k_lossrow<<<NROWS, 256, 0, stream>>>(logits, targets, nll);
  k_lossfinal<<<1, 256, 0, stream>>>(nll, targets, loss);
}

// Round 2
// 8314.228 us; speedup vs baseline: 1.4819x; 1.4819x over previous
//
#include <hip/hip_runtime.h>
#include <math.h>

// GPT forward w/ learned token pruning.
// Mask path numerics: imp ~1e-3 vs th ~1e-4 with ~0.3% rel spacing near the
// crossing -> plain bf16 GEMMs would flip mask bits. Layer GEMMs use
// split-bf16 3-term MFMA (err ~2^-17 rel, fp32-like). LM head (no mask
// dependency) uses plain bf16 MFMA. QK^T/PV/softmax stay fp32.

#define LNUM 12
#define HNUM 12
#define CDIM 768
#define VDIM 50304
#define TDIM 1024
#define BDIM 2
#define NROWS 2048   // B*T
#define LDSK 40      // LDS row stride (bf16 elems) for 32-wide k tiles

typedef __attribute__((ext_vector_type(8))) short short8;
typedef __attribute__((ext_vector_type(4))) float floatx4;
typedef __attribute__((ext_vector_type(4))) unsigned short ushort4v;
typedef __attribute__((ext_vector_type(8))) unsigned short ushort8v;

__device__ __forceinline__ unsigned short f2bf_rne(float f) {
  unsigned u = __float_as_uint(f);
  u += 0x7fff + ((u >> 16) & 1);
  return (unsigned short)(u >> 16);
}
__device__ __forceinline__ float bf2f(unsigned short h) {
  return __uint_as_float(((unsigned)h) << 16);
}

// ---------- block reduction (256 threads) ----------
__device__ __forceinline__ float bred(float v, int op) {  // op: 0 sum, 1 max
  __shared__ float red[256];
  const int tid = threadIdx.x;
  red[tid] = v;
  __syncthreads();
#pragma unroll
  for (int s = 128; s > 0; s >>= 1) {
    if (tid < s) {
      float o = red[tid + s];
      red[tid] = op ? fmaxf(red[tid], o) : (red[tid] + o);
    }
    __syncthreads();
  }
  float r = red[0];
  __syncthreads();
  return r;
}

// ---------- embedding + am init ----------
__global__ void k_embed(const int* __restrict__ idx, const float* __restrict__ wte,
                        const float* __restrict__ wpe, float* __restrict__ x,
                        float* __restrict__ am) {
  const int row = blockIdx.x;
  const int t = row & (TDIM - 1);
  const long tok = idx[row];
  const float* src = wte + tok * CDIM;
  const float* pp = wpe + (long)t * CDIM;
  float* dst = x + (long)row * CDIM;
  for (int c = threadIdx.x; c < CDIM; c += 256) dst[c] = src[c] + pp[c];
  if (threadIdx.x == 0) am[row] = 1.0f;
}

// ---------- layernorm ----------
__global__ void k_layernorm(const float* __restrict__ in, const float* __restrict__ w,
                            const float* __restrict__ b, float* __restrict__ out) {
  const long row = blockIdx.x;
  const int tid = threadIdx.x;
  const float* xr = in + row * CDIM;
  float v0 = xr[tid], v1 = xr[tid + 256], v2 = xr[tid + 512];
  float mean = bred(v0 + v1 + v2, 0) * (1.0f / CDIM);
  float d0 = v0 - mean, d1 = v1 - mean, d2 = v2 - mean;
  float var = bred(d0 * d0 + d1 * d1 + d2 * d2, 0) * (1.0f / CDIM);
  float inv = 1.0f / sqrtf(var + 1e-5f);
  float* orow = out + row * CDIM;
  orow[tid]       = d0 * inv * w[tid]       + b[tid];
  orow[tid + 256] = d1 * inv * w[tid + 256] + b[tid + 256];
  orow[tid + 512] = d2 * inv * w[tid + 512] + b[tid + 512];
}

// ---------- fp32 GEMM (used for QK^T and PV only) ----------
template <int BT, int ACT>
__global__ __launch_bounds__(256) void k_gemm(
    const float* __restrict__ A, const float* __restrict__ B,
    const float* __restrict__ bias, float* __restrict__ C,
    int K, int lda, int ldb, int ldc,
    long sAb, long sAh, long sBb, long sBh, long sCb, long sCh,
    int Hb, float alpha, int beta) {
  const int bid = blockIdx.z;
  const int bb = bid / Hb, hh = bid - bb * Hb;
  A += bb * sAb + hh * sAh;
  B += bb * sBb + hh * sBh;
  C += bb * sCb + hh * sCh;
  const int m0 = blockIdx.y << 6, n0 = blockIdx.x << 6;
  __shared__ float As[16][68];
  __shared__ float Bs[16][68];
  const int tid = threadIdx.x;
  const int r0 = (tid >> 4) << 2;
  const int c0 = (tid & 15) << 2;
  const int lr = tid >> 2;
  const int lk = (tid & 3) << 2;
  const int bk = tid >> 4;
  const int bn = (tid & 15) << 2;
  float acc[4][4] = {{0.f, 0.f, 0.f, 0.f}, {0.f, 0.f, 0.f, 0.f},
                     {0.f, 0.f, 0.f, 0.f}, {0.f, 0.f, 0.f, 0.f}};
  for (int k0 = 0; k0 < K; k0 += 16) {
    float4 av = *(const float4*)(A + (long)(m0 + lr) * lda + (k0 + lk));
    As[lk][lr] = av.x; As[lk + 1][lr] = av.y; As[lk + 2][lr] = av.z; As[lk + 3][lr] = av.w;
    if (BT) {
      float4 bv = *(const float4*)(B + (long)(n0 + lr) * ldb + (k0 + lk));
      Bs[lk][lr] = bv.x; Bs[lk + 1][lr] = bv.y; Bs[lk + 2][lr] = bv.z; Bs[lk + 3][lr] = bv.w;
    } else {
      *(float4*)&Bs[bk][bn] = *(const float4*)(B + (long)(k0 + bk) * ldb + (n0 + bn));
    }
    __syncthreads();
#pragma unroll
    for (int kk = 0; kk < 16; ++kk) {
      float4 a = *(const float4*)&As[kk][r0];
      float4 bv = *(const float4*)&Bs[kk][c0];
      acc[0][0] += a.x * bv.x; acc[0][1] += a.x * bv.y; acc[0][2] += a.x * bv.z; acc[0][3] += a.x * bv.w;
      acc[1][0] += a.y * bv.x; acc[1][1] += a.y * bv.y; acc[1][2] += a.y * bv.z; acc[1][3] += a.y * bv.w;
      acc[2][0] += a.z * bv.x; acc[2][1] += a.z * bv.y; acc[2][2] += a.z * bv.z; acc[2][3] += a.z * bv.w;
      acc[3][0] += a.w * bv.x; acc[3][1] += a.w * bv.y; acc[3][2] += a.w * bv.z; acc[3][3] += a.w * bv.w;
    }
    __syncthreads();
  }
  float4 bs4 = make_float4(0.f, 0.f, 0.f, 0.f);
  if (bias) bs4 = *(const float4*)(bias + n0 + c0);
#pragma unroll
  for (int i = 0; i < 4; ++i) {
    float* cp = C + (long)(m0 + r0 + i) * ldc + (n0 + c0);
    float4 prev = make_float4(0.f, 0.f, 0.f, 0.f);
    if (beta) prev = *(const float4*)cp;
    float4 o;
    o.x = prev.x + alpha * acc[i][0] + bs4.x;
    o.y = prev.y + alpha * acc[i][1] + bs4.y;
    o.z = prev.z + alpha * acc[i][2] + bs4.z;
    o.w = prev.w + alpha * acc[i][3] + bs4.w;
    if (ACT == 1) {
      o.x = 0.5f * o.x * (1.0f + erff(o.x * 0.70710678118654752f));
      o.y = 0.5f * o.y * (1.0f + erff(o.y * 0.70710678118654752f));
      o.z = 0.5f * o.z * (1.0f + erff(o.z * 0.70710678118654752f));
      o.w = 0.5f * o.w * (1.0f + erff(o.w * 0.70710678118654752f));
    }
    *(float4*)cp = o;
  }
}

// ---------- MFMA GEMM, split-bf16 (TERMS=3) or plain bf16 (TERMS=1) ----------
// C[M,N] = beta*C + A[M,K] @ B  (+bias, opt GELU).  A row-major (lda).
// BT=0: B is K x N row-major (ldb=N).  BT=1: B is N x K row-major (ldb=K).
// 128x128 tile, BK=32, 256 thr = 4 waves (2x2), each wave 4x4 frags of
// 16x16x32. fp32 inputs are converted to bf16 hi/lo during LDS staging.
// GS=1 swaps grid x/y (m fastest) for B-tile L2 reuse.
template <int BT, int TERMS, int ACT, int GS>
__global__ __launch_bounds__(256) void k_gemm_mfma(
    const float* __restrict__ A, const float* __restrict__ B,
    const float* __restrict__ bias, float* __restrict__ C,
    int K, int lda, int ldb, int ldc, int beta) {
  const int m0 = (GS ? blockIdx.x : blockIdx.y) << 7;
  const int n0 = (GS ? blockIdx.y : blockIdx.x) << 7;
  __shared__ unsigned short sm[(TERMS > 1 ? 4 : 2) * 128 * LDSK];
  unsigned short* As_hi = sm;
  unsigned short* As_lo = (TERMS > 1) ? (sm + 128 * LDSK) : sm;
  unsigned short* Bs_hi = sm + (TERMS > 1 ? 2 : 1) * 128 * LDSK;
  unsigned short* Bs_lo = (TERMS > 1) ? (Bs_hi + 128 * LDSK) : Bs_hi;
  const int tid = threadIdx.x;
  const int lane = tid & 63, wave = tid >> 6;
  const int wm = (wave & 1) << 6, wn = (wave >> 1) << 6;
  const int fr = lane & 15;          // frag row (A: m, B: n)
  const int fk = (lane >> 4) << 3;   // frag k offset: 0,8,16,24
  const int ar = tid >> 1, ak = (tid & 1) << 4;   // A/BT staging
  const int bn = tid & 31, bk = (tid >> 5) << 2;  // B (BT=0) staging

  floatx4 acc[4][4];
#pragma unroll
  for (int i = 0; i < 4; ++i)
#pragma unroll
    for (int j = 0; j < 4; ++j) acc[i][j] = (floatx4)(0.0f);

  for (int k0 = 0; k0 < K; k0 += 32) {
    // ---- stage A (128 x 32) ----
    {
      const float* ap = A + (long)(m0 + ar) * lda + (k0 + ak);
      float4 f0 = *(const float4*)(ap);
      float4 f1 = *(const float4*)(ap + 4);
      float4 f2 = *(const float4*)(ap + 8);
      float4 f3 = *(const float4*)(ap + 12);
      float va[16] = {f0.x, f0.y, f0.z, f0.w, f1.x, f1.y, f1.z, f1.w,
                      f2.x, f2.y, f2.z, f2.w, f3.x, f3.y, f3.z, f3.w};
      ushort8v h0, h1, l0, l1;
#pragma unroll
      for (int i = 0; i < 8; ++i) {
        unsigned short hA = f2bf_rne(va[i]);
        unsigned short hB = f2bf_rne(va[8 + i]);
        h0[i] = hA; h1[i] = hB;
        if (TERMS > 1) {
          l0[i] = f2bf_rne(va[i] - bf2f(hA));
          l1[i] = f2bf_rne(va[8 + i] - bf2f(hB));
        }
      }
      *(ushort8v*)&As_hi[ar * LDSK + ak]     = h0;
      *(ushort8v*)&As_hi[ar * LDSK + ak + 8] = h1;
      if (TERMS > 1) {
        *(ushort8v*)&As_lo[ar * LDSK + ak]     = l0;
        *(ushort8v*)&As_lo[ar * LDSK + ak + 8] = l1;
      }
    }
    // ---- stage B (as [n][k] in LDS) ----
    if (BT) {  // B is N x K row-major: same pattern as A
      const float* bp = B + (long)(n0 + ar) * ldb + (k0 + ak);
      float4 f0 = *(const float4*)(bp);
      float4 f1 = *(const float4*)(bp + 4);
      float4 f2 = *(const float4*)(bp + 8);
      float4 f3 = *(const float4*)(bp + 12);
      float vb[16] = {f0.x, f0.y, f0.z, f0.w, f1.x, f1.y, f1.z, f1.w,
                      f2.x, f2.y, f2.z, f2.w, f3.x, f3.y, f3.z, f3.w};
      ushort8v h0, h1, l0, l1;
#pragma unroll
      for (int i = 0; i < 8; ++i) {
        unsigned short hA = f2bf_rne(vb[i]);
        unsigned short hB = f2bf_rne(vb[8 + i]);
        h0[i] = hA; h1[i] = hB;
        if (TERMS > 1) {
          l0[i] = f2bf_rne(vb[i] - bf2f(hA));
          l1[i] = f2bf_rne(vb[8 + i] - bf2f(hB));
        }
      }
      *(ushort8v*)&Bs_hi[ar * LDSK + ak]     = h0;
      *(ushort8v*)&Bs_hi[ar * LDSK + ak + 8] = h1;
      if (TERMS > 1) {
        *(ushort8v*)&Bs_lo[ar * LDSK + ak]     = l0;
        *(ushort8v*)&Bs_lo[ar * LDSK + ak + 8] = l1;
      }
    } else {  // B is K x N row-major: scalar loads + register transpose
      float bvv[4][4];
#pragma unroll
      for (int j = 0; j < 4; ++j)
#pragma unroll
        for (int r = 0; r < 4; ++r)
          bvv[j][r] = B[(long)(k0 + bk + r) * ldb + (n0 + bn + 32 * j)];
#pragma unroll
      for (int j = 0; j < 4; ++j) {
        ushort4v hv, lv;
#pragma unroll
        for (int r = 0; r < 4; ++r) {
          unsigned short hh = f2bf_rne(bvv[j][r]);
          hv[r] = hh;
          if (TERMS > 1) lv[r] = f2bf_rne(bvv[j][r] - bf2f(hh));
        }
        *(ushort4v*)&Bs_hi[(bn + 32 * j) * LDSK + bk] = hv;
        if (TERMS > 1) *(ushort4v*)&Bs_lo[(bn + 32 * j) * LDSK + bk] = lv;
      }
    }
    __syncthreads();
    // ---- fragments + MFMA ----
    short8 a_hi[4], a_lo[4], b_hi[4], b_lo[4];
#pragma unroll
    for (int i = 0; i < 4; ++i) {
      a_hi[i] = *(const short8*)&As_hi[(wm + i * 16 + fr) * LDSK + fk];
      b_hi[i] = *(const short8*)&Bs_hi[(wn + i * 16 + fr) * LDSK + fk];
      if (TERMS > 1) {
        a_lo[i] = *(const short8*)&As_lo[(wm + i * 16 + fr) * LDSK + fk];
        b_lo[i] = *(const short8*)&Bs_lo[(wn + i * 16 + fr) * LDSK + fk];
      }
    }
#pragma unroll
    for (int i = 0; i < 4; ++i)
#pragma unroll
      for (int j = 0; j < 4; ++j) {
        acc[i][j] = __builtin_amdgcn_mfma_f32_16x16x32_bf16(a_hi[i], b_hi[j], acc[i][j], 0, 0, 0);
        if (TERMS > 1) {
          acc[i][j] = __builtin_amdgcn_mfma_f32_16x16x32_bf16(a_hi[i], b_lo[j], acc[i][j], 0, 0, 0);
          acc[i][j] = __builtin_amdgcn_mfma_f32_16x16x32_bf16(a_lo[i], b_hi[j], acc[i][j], 0, 0, 0);
        }
      }
    __syncthreads();
  }
  // ---- epilogue: C/D map col=lane&15, row=(lane>>4)*4+reg ----
  const int er = (lane >> 4) << 2;
  const int ec = lane & 15;
#pragma unroll
  for (int j = 0; j < 4; ++j) {
    const int col = n0 + wn + j * 16 + ec;
    const float bsv = bias ? bias[col] : 0.0f;
#pragma unroll
    for (int i = 0; i < 4; ++i) {
#pragma unroll
      for (int r = 0; r < 4; ++r) {
        float* cp = C + (long)(m0 + wm + i * 16 + er + r) * ldc + col;
        float o = acc[i][j][r] + bsv + (beta ? *cp : 0.0f);
        if (ACT == 1) o = 0.5f * o * (1.0f + erff(o * 0.70710678118654752f));
        *cp = o;
      }
    }
  }
}

// ---------- masked softmax over keys ----------
__global__ void k_softmax(float* __restrict__ att, const float* __restrict__ am) {
  const int q = blockIdx.x;
  const int bh = blockIdx.y;
  const int b = bh / HNUM;
  float* row = att + ((long)bh * TDIM + q) * TDIM;
  const float* amr = am + b * TDIM;
  const int tid = threadIdx.x;
  float lv[4];
  bool valid[4];
  float mx = -INFINITY;
#pragma unroll
  for (int i = 0; i < 4; ++i) {
    const int k = tid + (i << 8);
    const bool ok = (k <= q) && (amr[k] > 0.0f);
    valid[i] = ok;
    lv[i] = ok ? row[k] : -INFINITY;
    mx = fmaxf(mx, lv[i]);
  }
  mx = bred(mx, 1);
  float sum = 0.f;
#pragma unroll
  for (int i = 0; i < 4; ++i) {
    lv[i] = valid[i] ? expf(lv[i] - mx) : 0.0f;
    sum += lv[i];
  }
  sum = bred(sum, 0);
  const float inv = sum > 0.f ? 1.0f / sum : 0.0f;
#pragma unroll
  for (int i = 0; i < 4; ++i) row[tid + (i << 8)] = lv[i] * inv;
}

// ---------- imp[b,k] partial column sums of att ----------
__global__ void k_impsum(const float* __restrict__ att, float* __restrict__ imp) {
  const int h = blockIdx.x >> 2, qc = blockIdx.x & 3;
  const int b = blockIdx.z;
  const int k = (blockIdx.y << 8) + threadIdx.x;
  const float* base = att + (((long)(b * HNUM + h) * TDIM) + (qc << 8)) * TDIM + k;
  float s = 0.f;
#pragma unroll 4
  for (int q = 0; q < 256; ++q) s += base[(long)q * TDIM];
  atomicAdd(&imp[b * TDIM + k], s);
}

// ---------- threshold mask ----------
__global__ void k_mask(const float* __restrict__ imp, const float* __restrict__ thp,
                       float* __restrict__ am, float* __restrict__ x) {
  const int row = blockIdx.x;
  const int t = row & (TDIM - 1);
  const float impv = imp[row] * (1.0f / (HNUM * TDIM));
  float pm = (impv >= *thp) ? 1.0f : 0.0f;
  if (t >= TDIM - 64) pm = 1.0f;
  const float cm = am[row] * pm;
  float* xr = x + (long)row * CDIM;
  const int tid = threadIdx.x;
  xr[tid] *= cm;
  xr[tid + 256] *= cm;
  xr[tid + 512] *= cm;
  if (tid == 0) am[row] = cm;
}

// ---------- loss ----------
__global__ void k_lossrow(const float* __restrict__ logits, const int* __restrict__ tgt,
                          float* __restrict__ nll) {
  const int row = blockIdx.x;
  const float* lr = logits + (long)row * VDIM;
  const int tid = threadIdx.x;
  float mx = -INFINITY;
  for (int k = tid; k < VDIM; k += 256) mx = fmaxf(mx, lr[k]);
  mx = bred(mx, 1);
  float s = 0.f;
  for (int k = tid; k < VDIM; k += 256) s += expf(lr[k] - mx);
  s = bred(s, 0);
  if (tid == 0) {
    const int t = tgt[row];
    nll[row] = (t != -1) ? -(lr[t] - mx - logf(s)) : 0.0f;
  }
}

__global__ void k_lossfinal(const float* __restrict__ nll, const int* __restrict__ tgt,
                            float* __restrict__ out) {
  const int tid = threadIdx.x;
  float s = 0.f, cnt = 0.f;
  for (int r = tid; r < NROWS; r += 256) {
    s += nll[r];
    cnt += (tgt[r] != -1) ? 1.f : 0.f;
  }
  s = bred(s, 0);
  cnt = bred(cnt, 0);
  if (tid == 0) out[0] = s / cnt;
}

extern "C" void kernel_launch(void* const* d_in, const int* in_sizes, int n_in,
                              void* d_out, int out_size, void* d_ws, size_t ws_size,
                              hipStream_t stream) {
  (void)in_sizes; (void)n_in; (void)out_size; (void)ws_size;
  const int* idx      = (const int*)d_in[0];
  const int* targets  = (const int*)d_in[1];
  const float* wte    = (const float*)d_in[2];
  const float* wpe    = (const float*)d_in[3];
  const float* ln1_w  = (const float*)d_in[4];
  const float* ln1_b  = (const float*)d_in[5];
  const float* attn_w = (const float*)d_in[6];
  const float* attn_b = (const float*)d_in[7];
  const float* proj_w = (const float*)d_in[8];
  const float* proj_b = (const float*)d_in[9];
  const float* ln2_w  = (const float*)d_in[10];
  const float* ln2_b  = (const float*)d_in[11];
  const float* fc_w   = (const float*)d_in[12];
  const float* fc_b   = (const float*)d_in[13];
  const float* mlp_w  = (const float*)d_in[14];
  const float* mlp_b  = (const float*)d_in[15];
  const float* thres  = (const float*)d_in[16];
  const float* lnf_w  = (const float*)d_in[17];
  const float* lnf_b  = (const float*)d_in[18];
  float* logits = (float*)d_out;
  float* loss = logits + (long)NROWS * VDIM;

  float* x    = (float*)d_ws;
  float* h    = x + (long)NROWS * CDIM;
  float* qkv  = h + (long)NROWS * CDIM;
  float* att  = qkv + (long)NROWS * 3 * CDIM;
  float* ybuf = att + (long)BDIM * HNUM * TDIM * TDIM;
  float* act  = ybuf + (long)NROWS * CDIM;
  float* am   = act + (long)NROWS * 4 * CDIM;
  float* imp  = am + NROWS;
  float* nll  = imp + NROWS;

  k_embed<<<NROWS, 256, 0, stream>>>(idx, wte, wpe, x, am);

  for (int l = 0; l < LNUM; ++l) {
    k_layernorm<<<NROWS, 256, 0, stream>>>(x, ln1_w + l * CDIM, ln1_b + l * CDIM, h);
    // qkv = h @ attn_w[l] + attn_b[l]   (2048x2304, K=768) split-bf16 MFMA
    k_gemm_mfma<0, 3, 0, 0><<<dim3(18, 16), 256, 0, stream>>>(
        h, attn_w + (long)l * CDIM * 3 * CDIM, attn_b + (long)l * 3 * CDIM, qkv,
        768, 768, 2304, 2304, 0);
    // scores = q @ k^T / 8   (fp32)
    k_gemm<1, 0><<<dim3(16, 16, 24), 256, 0, stream>>>(
        qkv, qkv + CDIM, nullptr, att,
        64, 2304, 2304, 1024,
        (long)TDIM * 3 * CDIM, 64, (long)TDIM * 3 * CDIM, 64,
        (long)HNUM * TDIM * TDIM, (long)TDIM * TDIM, HNUM, 0.125f, 0);
    k_softmax<<<dim3(TDIM, BDIM * HNUM), 256, 0, stream>>>(att, am);
    hipMemsetAsync(imp, 0, NROWS * sizeof(float), stream);
    k_impsum<<<dim3(HNUM * 4, 4, BDIM), 256, 0, stream>>>(att, imp);
    // y = att @ v   (fp32)
    k_gemm<0, 0><<<dim3(1, 16, 24), 256, 0, stream>>>(
        att, qkv + 2 * CDIM, nullptr, ybuf,
        1024, 1024, 2304, 768,
        (long)HNUM * TDIM * TDIM, (long)TDIM * TDIM, (long)TDIM * 3 * CDIM, 64,
        (long)TDIM * CDIM, 64, HNUM, 1.0f, 0);
    // x += ybuf @ proj_w[l] + proj_b[l]  split-bf16 MFMA
    k_gemm_mfma<0, 3, 0, 0><<<dim3(6, 16), 256, 0, stream>>>(
        ybuf, proj_w + (long)l * CDIM * CDIM, proj_b + (long)l * CDIM, x,
        768, 768, 768, 768, 1);
    k_mask<<<NROWS, 256, 0, stream>>>(imp, thres + l, am, x);
    k_layernorm<<<NROWS, 256, 0, stream>>>(x, ln2_w + l * CDIM, ln2_b + l * CDIM, h);
    // act = gelu(h @ fc_w[l] + fc_b[l])  split-bf16 MFMA
    k_gemm_mfma<0, 3, 1, 0><<<dim3(24, 16), 256, 0, stream>>>(
        h, fc_w + (long)l * CDIM * 4 * CDIM, fc_b + (long)l * 4 * CDIM, act,
        768, 768, 3072, 3072, 0);
    // x += act @ mlp_w[l] + mlp_b[l]  split-bf16 MFMA
    k_gemm_mfma<0, 3, 0, 0><<<dim3(6, 16), 256, 0, stream>>>(
        act, mlp_w + (long)l * 4 * CDIM * CDIM, mlp_b + (long)l * CDIM, x,
        3072, 3072, 768, 768, 1);
  }

  k_layernorm<<<NROWS, 256, 0, stream>>>(x, lnf_w, lnf_b, h);
  // logits = h @ wte^T  (2048x50304, K=768): plain bf16 MFMA, BT (wte is NxK),
  // grid-swapped so the 16 m-tiles sharing a wte n-tile are co-resident.
  k_gemm_mfma<1, 1, 0, 1><<<dim3(16, 393), 256, 0, stream>>>(
      h, wte, nullptr, logits,
      768, 768, 768, VDIM, 0);
  k_lossrow<<<NROWS, 256, 0, stream>>>(logits, targets, nll);
  k_lossfinal<<<1, 256, 0, stream>>>(nll, targets, loss);
}